// Round 2
// baseline (2081.660 us; speedup 1.0000x reference)
//
#include <hip/hip_runtime.h>

#define B_   4096
#define T_   1024
#define IN_  5
#define H_   16
#define L_   4
#define OUT_ 150

__device__ __forceinline__ float fast_rcp(float x) { return __builtin_amdgcn_rcpf(x); }

__device__ __forceinline__ float sigm(float v) {
    // 1/(1+e^-v); overflow-safe: exp(+inf)->inf->rcp->0
    float e = __expf(-v);
    return fast_rcp(1.0f + e);
}

__device__ __forceinline__ float tanh_fast(float v) {
    // tanh(v) = sign(v)*(1-e)/(1+e), e = exp(-2|v|)  (no overflow)
    float e = __expf(-2.0f * fabsf(v));
    float t = (1.0f - e) * fast_rcp(1.0f + e);
    return copysignf(t, v);
}

struct V16 { float v[H_]; };

// 16 same-type scalar LDS reads (LSV merges to ds_read_b128 legally; ordering
// vs float stores preserved since types match -> must-may-alias)
__device__ __forceinline__ V16 ld16(const float* p) {
    V16 r;
#pragma unroll
    for (int k = 0; k < H_; ++k) r.v[k] = p[k];
    return r;
}

__device__ __forceinline__ float dot16(const float (&w)[H_], const V16& x, float init) {
    float a = init, b = 0.0f, c = 0.0f, d = 0.0f;
#pragma unroll
    for (int k = 0; k < H_; k += 4) {
        a = fmaf(w[k + 0], x.v[k + 0], a);
        b = fmaf(w[k + 1], x.v[k + 1], b);
        c = fmaf(w[k + 2], x.v[k + 2], c);
        d = fmaf(w[k + 3], x.v[k + 3], d);
    }
    return (a + b) + (c + d);
}

__global__ __launch_bounds__(256) void gru_fused(
    const float* __restrict__ x_in,
    const float* __restrict__ Wih0, const float* __restrict__ Whh0,
    const float* __restrict__ bih0, const float* __restrict__ bhh0,
    const float* __restrict__ Wih1, const float* __restrict__ Whh1,
    const float* __restrict__ bih1, const float* __restrict__ bhh1,
    const float* __restrict__ Wih2, const float* __restrict__ Whh2,
    const float* __restrict__ bih2, const float* __restrict__ bhh2,
    const float* __restrict__ Wih3, const float* __restrict__ Whh3,
    const float* __restrict__ bih3, const float* __restrict__ bhh3,
    const float* __restrict__ fcw,  const float* __restrict__ fcb,
    float* __restrict__ out)
{
    // per-wave h broadcast buffer: hs[wave][layer][16] (plain float only!)
    __shared__ __align__(16) float hs[4][L_][H_];

    const int wv   = threadIdx.x >> 6;
    const int lane = threadIdx.x & 63;
    const int g    = lane >> 4;          // 0=r,1=z,2=n rows; 3 duplicates n
    const int j    = lane & 15;
    const int row  = ((g < 3) ? g : 2) * H_ + j;

    const int b = blockIdx.x * 4 + wv;

    // ---- per-lane weight rows in registers ----
    float wi0[IN_], wh0[H_];
    float wi1[H_], wh1[H_];
    float wi2[H_], wh2[H_];
    float wi3[H_], wh3[H_];
    float bi[4], bh[4];

#pragma unroll
    for (int k = 0; k < IN_; ++k) wi0[k] = Wih0[row * IN_ + k];
#pragma unroll
    for (int k = 0; k < H_; ++k) {
        wh0[k] = Whh0[row * H_ + k];
        wi1[k] = Wih1[row * H_ + k];
        wh1[k] = Whh1[row * H_ + k];
        wi2[k] = Wih2[row * H_ + k];
        wh2[k] = Whh2[row * H_ + k];
        wi3[k] = Wih3[row * H_ + k];
        wh3[k] = Whh3[row * H_ + k];
    }
    bi[0] = bih0[row]; bi[1] = bih1[row]; bi[2] = bih2[row]; bi[3] = bih3[row];
    bh[0] = bhh0[row]; bh[1] = bhh1[row]; bh[2] = bhh2[row]; bh[3] = bhh3[row];

    // old-h_j held in registers (every lane's tail value IS h^l_j for its j)
    float hold0 = 0.0f, hold1 = 0.0f, hold2 = 0.0f, hold3 = 0.0f;

    // zero the broadcast buffer (own wave only; same-wave DS is program-order)
    if (lane < H_) {
#pragma unroll
        for (int l = 0; l < L_; ++l) hs[wv][l][j] = 0.0f;
    }
    asm volatile("" ::: "memory");

    const float* hsl0 = &hs[wv][0][0];
    const float* hsl1 = &hs[wv][1][0];
    const float* hsl2 = &hs[wv][2][0];
    const float* hsl3 = &hs[wv][3][0];

    const float* xbase = x_in + (size_t)b * T_ * IN_;
    float xc0 = xbase[0], xc1 = xbase[1], xc2 = xbase[2], xc3 = xbase[3], xc4 = xbase[4];

    // gate tail: r/z/n exchange + h update (pure intra-wave register dataflow)
#define LAYER_TAIL(LIDX, HOLD)                                            \
    {                                                                     \
        float s_  = sigm(xg + hg);                                        \
        float rv_ = __shfl(s_, j, 64);                                    \
        float n_  = tanh_fast(fmaf(rv_, hg, xg));                         \
        float zv_ = __shfl(s_, 16 + j, 64);                               \
        float nv_ = __shfl(n_, 32 + j, 64);                               \
        float hn_ = fmaf(zv_, HOLD - nv_, nv_);                           \
        HOLD = hn_;                                                       \
        if (lane < H_) hs[wv][LIDX][j] = hn_;                             \
        asm volatile("" ::: "memory");                                    \
    }

#pragma unroll 1
    for (int t = 0; t < T_; ++t) {
        const int tn = (t + 1 < T_) ? (t + 1) : (T_ - 1);
        const float* xp = xbase + tn * IN_;
        float nx0 = xp[0], nx1 = xp[1], nx2 = xp[2], nx3 = xp[3], nx4 = xp[4];

        // ---- layer 0 (d=5, x from global) ----
        {
            V16 h0 = ld16(hsl0);                    // old h^0
            float xg = bi[0];
            xg = fmaf(wi0[0], xc0, xg);
            xg = fmaf(wi0[1], xc1, xg);
            xg = fmaf(wi0[2], xc2, xg);
            xg = fmaf(wi0[3], xc3, xg);
            xg = fmaf(wi0[4], xc4, xg);
            float hg = dot16(wh0, h0, bh[0]);
            LAYER_TAIL(0, hold0)
        }
        // ---- layer 1 ----
        {
            V16 x1 = ld16(hsl0);                    // new h^0 (just stored)
            V16 h1 = ld16(hsl1);                    // old h^1
            float xg = dot16(wi1, x1, bi[1]);
            float hg = dot16(wh1, h1, bh[1]);
            LAYER_TAIL(1, hold1)
        }
        // ---- layer 2 ----
        {
            V16 x2 = ld16(hsl1);
            V16 h2 = ld16(hsl2);
            float xg = dot16(wi2, x2, bi[2]);
            float hg = dot16(wh2, h2, bh[2]);
            LAYER_TAIL(2, hold2)
        }
        // ---- layer 3 ----
        {
            V16 x3 = ld16(hsl2);
            V16 h3 = ld16(hsl3);
            float xg = dot16(wi3, x3, bi[3]);
            float hg = dot16(wh3, h3, bh[3]);
            LAYER_TAIL(3, hold3)
        }

        xc0 = nx0; xc1 = nx1; xc2 = nx2; xc3 = nx3; xc4 = nx4;
    }
#undef LAYER_TAIL

    // ---- FC epilogue: hidden = [h^0_T | h^1_T | h^2_T | h^3_T] ----
    float hid[L_ * H_];
#pragma unroll
    for (int k = 0; k < H_; ++k) {
        hid[0 * H_ + k] = hsl0[k];
        hid[1 * H_ + k] = hsl1[k];
        hid[2 * H_ + k] = hsl2[k];
        hid[3 * H_ + k] = hsl3[k];
    }
    float* ob = out + (size_t)b * OUT_;
#pragma unroll
    for (int rep = 0; rep < 3; ++rep) {
        int o = lane + rep * 64;
        if (o < OUT_) {
            const float* wr = fcw + o * (L_ * H_);
            float acc = fcb[o];
#pragma unroll
            for (int k = 0; k < L_ * H_; ++k) acc = fmaf(wr[k], hid[k], acc);
            ob[o] = acc;
        }
    }
}

extern "C" void kernel_launch(void* const* d_in, const int* in_sizes, int n_in,
                              void* d_out, int out_size, void* d_ws, size_t ws_size,
                              hipStream_t stream) {
    const float* xin = (const float*)d_in[0];
    // d_in[1] = target_seq: unused by the reference output
    gru_fused<<<B_ / 4, 256, 0, stream>>>(
        xin,
        (const float*)d_in[2],  (const float*)d_in[3],  (const float*)d_in[4],  (const float*)d_in[5],
        (const float*)d_in[6],  (const float*)d_in[7],  (const float*)d_in[8],  (const float*)d_in[9],
        (const float*)d_in[10], (const float*)d_in[11], (const float*)d_in[12], (const float*)d_in[13],
        (const float*)d_in[14], (const float*)d_in[15], (const float*)d_in[16], (const float*)d_in[17],
        (const float*)d_in[18], (const float*)d_in[19],
        (float*)d_out);
}